// Round 1
// baseline (1221.802 us; speedup 1.0000x reference)
//
#include <hip/hip_runtime.h>

// ---------------------------------------------------------------------------
// GIN forward on MI355X.
// Pipeline per call:
//   CSR build (zero, hist, scan x3, fill)
//   per layer: agg (wave/node, fp32 -> bf16 hi/lo split)
//              prep_w1 (W1 -> transposed bf16 hi/lo, zero col stats)
//              gemm<1> (split-bf16 MFMA, bias+leaky, writes h1 hi/lo + col stats)
//              prep_w2 (fold BN into W2 -> Wt2' hi/lo, b2')
//              gemm<2> (split-bf16 MFMA, bias+leaky, writes fp32 hbuf)
//   graph_bounds, pool (wave/graph), pool_stats (BN fold), final_fc
// ---------------------------------------------------------------------------

typedef __attribute__((ext_vector_type(8))) __bf16 bf16x8;
typedef __attribute__((ext_vector_type(4))) float  f32x4;

__device__ __forceinline__ unsigned short f2bf(float f) {
    union { float f; unsigned int u; } v; v.f = f;
    unsigned int r = v.u + 0x7fffu + ((v.u >> 16) & 1u);
    return (unsigned short)(r >> 16);
}
__device__ __forceinline__ float bf2f(unsigned short h) {
    union { unsigned int u; float f; } v; v.u = ((unsigned int)h) << 16;
    return v.f;
}

// ------------------------------ CSR build ---------------------------------

__global__ void zero2_kernel(int* __restrict__ a, int* __restrict__ b, int n) {
    int i = blockIdx.x * 256 + threadIdx.x;
    if (i < n) { a[i] = 0; b[i] = 0; }
}

__global__ void hist_kernel(const int* __restrict__ dst, int* __restrict__ deg, int E) {
    int e = blockIdx.x * 256 + threadIdx.x;
    if (e < E) atomicAdd(&deg[dst[e]], 1);
}

__global__ void scan1_kernel(const int* __restrict__ deg, int* __restrict__ ofs,
                             int* __restrict__ bsum, int n) {
    __shared__ int sh[256];
    int tid = threadIdx.x;
    int i = blockIdx.x * 256 + tid;
    int v = (i < n) ? deg[i] : 0;
    sh[tid] = v;
    __syncthreads();
    for (int o = 1; o < 256; o <<= 1) {
        int tmp = (tid >= o) ? sh[tid - o] : 0;
        __syncthreads();
        sh[tid] += tmp;
        __syncthreads();
    }
    if (i < n) ofs[i] = sh[tid] - v;           // exclusive within block
    if (tid == 255) bsum[blockIdx.x] = sh[255];
}

__global__ void scan2_kernel(int* __restrict__ bsum, int nb) {
    __shared__ int sh[1024];
    int tid = threadIdx.x;
    int v = (tid < nb) ? bsum[tid] : 0;
    sh[tid] = v;
    __syncthreads();
    for (int o = 1; o < 1024; o <<= 1) {
        int tmp = (tid >= o) ? sh[tid - o] : 0;
        __syncthreads();
        sh[tid] += tmp;
        __syncthreads();
    }
    if (tid < nb) bsum[tid] = sh[tid] - v;     // exclusive
}

__global__ void scan3_kernel(int* __restrict__ ofs, const int* __restrict__ bsum,
                             int n, int Etot) {
    int i = blockIdx.x * 256 + threadIdx.x;
    if (i < n) ofs[i] += bsum[blockIdx.x];
    if (i == 0) ofs[n] = Etot;
}

__global__ void fill_kernel(const int* __restrict__ src, const int* __restrict__ dst,
                            const int* __restrict__ ofs, int* __restrict__ cur,
                            int* __restrict__ csr, int E) {
    int e = blockIdx.x * 256 + threadIdx.x;
    if (e >= E) return;
    int d = dst[e];
    int p = atomicAdd(&cur[d], 1);
    csr[ofs[d] + p] = src[e];
}

// --------------------------- aggregation ----------------------------------
// One wave per node: hin = h[i] + sum_{j in CSR[i]} h[src_j]; store bf16 hi/lo.

__global__ void agg_split(const float* __restrict__ h, const int* __restrict__ ofs,
                          const int* __restrict__ csr,
                          unsigned short* __restrict__ Ohi, unsigned short* __restrict__ Olo,
                          int n) {
    int node = (blockIdx.x << 2) + (threadIdx.x >> 6);
    if (node >= n) return;
    int lane = threadIdx.x & 63;
    const float2* base = (const float2*)h;
    float2 a = base[node * 64 + lane];
    float ax = a.x, ay = a.y;
    int e0 = ofs[node], e1 = ofs[node + 1];
    for (int j = e0; j < e1; ++j) {
        int s = csr[j];
        float2 v = base[s * 64 + lane];
        ax += v.x; ay += v.y;
    }
    unsigned short hx = f2bf(ax), hy = f2bf(ay);
    unsigned short lx = f2bf(ax - bf2f(hx)), ly = f2bf(ay - bf2f(hy));
    unsigned int ph = (unsigned int)hx | ((unsigned int)hy << 16);
    unsigned int pl = (unsigned int)lx | ((unsigned int)ly << 16);
    *(unsigned int*)(Ohi + node * 128 + lane * 2) = ph;
    *(unsigned int*)(Olo + node * 128 + lane * 2) = pl;
}

// --------------------------- weight prep ----------------------------------
// W [128k][128n] fp32 -> Bt hi/lo [128n][128k] bf16 (transposed). Also zero stats.

__global__ void prep_w1(const float* __restrict__ W, unsigned short* __restrict__ Bth,
                        unsigned short* __restrict__ Btl, float* __restrict__ colsum,
                        float* __restrict__ colsq) {
    int t = blockIdx.x * 256 + threadIdx.x;   // 64 blocks * 256 = 16384
    int n = t >> 7, k = t & 127;
    float v = W[k * 128 + n];
    unsigned short h = f2bf(v);
    Bth[t] = h;
    Btl[t] = f2bf(v - bf2f(h));
    if (blockIdx.x == 0 && threadIdx.x < 128) { colsum[threadIdx.x] = 0.f; colsq[threadIdx.x] = 0.f; }
}

// Fold BN(h1) into W2: W2'[k][n] = s[k]*W2[k][n]; b2'[n] = b2[n] + sum_k t[k]*W2[k][n]
__global__ void prep_w2(const float* __restrict__ W2, const float* __restrict__ b2,
                        const float* __restrict__ g1, const float* __restrict__ be1,
                        const float* __restrict__ colsum, const float* __restrict__ colsq,
                        unsigned short* __restrict__ Bth, unsigned short* __restrict__ Btl,
                        float* __restrict__ b2p, int nrows) {
    __shared__ float s[128], tt[128];
    int tid = threadIdx.x;
    if (tid < 128) {
        float mu = colsum[tid] / (float)nrows;
        float var = colsq[tid] / (float)nrows - mu * mu;
        float rs = rsqrtf(var + 1e-5f);
        float sc = rs * g1[tid];
        s[tid] = sc;
        tt[tid] = be1[tid] - mu * sc;
    }
    __syncthreads();
    for (int e = tid; e < 16384; e += 256) {
        int n = e >> 7, k = e & 127;
        float v = s[k] * W2[k * 128 + n];
        unsigned short h = f2bf(v);
        Bth[e] = h;
        Btl[e] = f2bf(v - bf2f(h));
    }
    if (tid < 128) {
        float a = b2[tid];
        for (int k = 0; k < 128; ++k) a += tt[k] * W2[k * 128 + tid];
        b2p[tid] = a;
    }
}

// ------------------------------- GEMM -------------------------------------
// C[N,128] = A[N,128] @ B[128,128], split-bf16 (Ah Bh + Ah Bl + Al Bh), MFMA 16x16x32.
// Block: 256 threads (4 waves). Wave w owns cols [w*32, w*32+32), block owns 128 rows.
// B frags held in registers (16 frags), A frags streamed from global (L2/L3 resident).
// STAGE 1: out = bf16 hi/lo split + column sum/sumsq stats. STAGE 2: out = fp32.

template <int STAGE>
__global__ void gemm_split(const unsigned short* __restrict__ Ah, const unsigned short* __restrict__ Al,
                           const unsigned short* __restrict__ Bh, const unsigned short* __restrict__ Bl,
                           const float* __restrict__ bias,
                           unsigned short* __restrict__ Ohi, unsigned short* __restrict__ Olo,
                           float* __restrict__ Of32,
                           float* __restrict__ colsum, float* __restrict__ colsq,
                           int nrows) {
    const int lane = threadIdx.x & 63;
    const int wv = threadIdx.x >> 6;
    const int l15 = lane & 15;
    const int lg = lane >> 4;          // 0..3
    const int colbase = wv * 32;
    const int rowbase = blockIdx.x * 128;

    // B fragments: B[k][n], lane holds k = ks*32 + lg*8 + j, n = colbase + nc*16 + l15.
    // Stored transposed in memory: Bt[n][k].
    bf16x8 bh[2][4], bl[2][4];
#pragma unroll
    for (int nc = 0; nc < 2; ++nc)
#pragma unroll
        for (int ks = 0; ks < 4; ++ks) {
            int n = colbase + nc * 16 + l15;
            int k = ks * 32 + lg * 8;
            bh[nc][ks] = *(const bf16x8*)(Bh + n * 128 + k);
            bl[nc][ks] = *(const bf16x8*)(Bl + n * 128 + k);
        }
    float bias0 = bias[colbase + l15];
    float bias1 = bias[colbase + 16 + l15];
    float s0 = 0.f, s1 = 0.f, q0 = 0.f, q1 = 0.f;

#pragma unroll 2
    for (int mr = 0; mr < 8; ++mr) {
        int arow = rowbase + mr * 16 + l15;
        int ar = (arow < nrows) ? arow : (nrows - 1);
        const unsigned short* pa = Ah + ar * 128 + lg * 8;
        const unsigned short* pl = Al + ar * 128 + lg * 8;
        bf16x8 ah[4], al[4];
#pragma unroll
        for (int ks = 0; ks < 4; ++ks) {
            ah[ks] = *(const bf16x8*)(pa + ks * 32);
            al[ks] = *(const bf16x8*)(pl + ks * 32);
        }
        f32x4 acc0 = {0.f, 0.f, 0.f, 0.f};
        f32x4 acc1 = {0.f, 0.f, 0.f, 0.f};
#pragma unroll
        for (int ks = 0; ks < 4; ++ks) {
            acc0 = __builtin_amdgcn_mfma_f32_16x16x32_bf16(ah[ks], bh[0][ks], acc0, 0, 0, 0);
            acc1 = __builtin_amdgcn_mfma_f32_16x16x32_bf16(ah[ks], bh[1][ks], acc1, 0, 0, 0);
            acc0 = __builtin_amdgcn_mfma_f32_16x16x32_bf16(ah[ks], bl[0][ks], acc0, 0, 0, 0);
            acc1 = __builtin_amdgcn_mfma_f32_16x16x32_bf16(ah[ks], bl[1][ks], acc1, 0, 0, 0);
            acc0 = __builtin_amdgcn_mfma_f32_16x16x32_bf16(al[ks], bh[0][ks], acc0, 0, 0, 0);
            acc1 = __builtin_amdgcn_mfma_f32_16x16x32_bf16(al[ks], bh[1][ks], acc1, 0, 0, 0);
        }
        // C/D layout: row = lg*4 + r, col = l15  (m89-verified)
        int orow0 = rowbase + mr * 16 + lg * 4;
#pragma unroll
        for (int r = 0; r < 4; ++r) {
            int orow = orow0 + r;
            if (orow < nrows) {
                float v0 = acc0[r] + bias0;
                v0 = v0 > 0.f ? v0 : 0.2f * v0;
                float v1 = acc1[r] + bias1;
                v1 = v1 > 0.f ? v1 : 0.2f * v1;
                int c0 = colbase + l15;
                int c1 = colbase + 16 + l15;
                if (STAGE == 1) {
                    unsigned short h0 = f2bf(v0);
                    Ohi[orow * 128 + c0] = h0;
                    Olo[orow * 128 + c0] = f2bf(v0 - bf2f(h0));
                    unsigned short h1 = f2bf(v1);
                    Ohi[orow * 128 + c1] = h1;
                    Olo[orow * 128 + c1] = f2bf(v1 - bf2f(h1));
                    s0 += v0; q0 += v0 * v0;
                    s1 += v1; q1 += v1 * v1;
                } else {
                    Of32[orow * 128 + c0] = v0;
                    Of32[orow * 128 + c1] = v1;
                }
            }
        }
    }
    if (STAGE == 1) {
        s0 += __shfl_xor(s0, 16); s0 += __shfl_xor(s0, 32);
        q0 += __shfl_xor(q0, 16); q0 += __shfl_xor(q0, 32);
        s1 += __shfl_xor(s1, 16); s1 += __shfl_xor(s1, 32);
        q1 += __shfl_xor(q1, 16); q1 += __shfl_xor(q1, 32);
        if (lg == 0) {
            atomicAdd(&colsum[colbase + l15], s0);
            atomicAdd(&colsq[colbase + l15], q0);
            atomicAdd(&colsum[colbase + 16 + l15], s1);
            atomicAdd(&colsq[colbase + 16 + l15], q1);
        }
    }
}

// ------------------------------ pooling -----------------------------------

__global__ void graph_bounds(const int* __restrict__ batch, int* __restrict__ gstart,
                             int n, int G) {
    int i = blockIdx.x * 256 + threadIdx.x;
    if (i >= n) return;
    int b = batch[i];
    if (i == 0) {
        for (int x = 0; x <= b; ++x) gstart[x] = 0;
    } else {
        int p = batch[i - 1];
        for (int x = p + 1; x <= b; ++x) gstart[x] = i;
    }
    if (i == n - 1) {
        for (int x = b + 1; x <= G; ++x) gstart[x] = n;
    }
}

__global__ void pool_kernel(const float* __restrict__ h, const int* __restrict__ gstart,
                            float* __restrict__ pooled, int G) {
    int g = (blockIdx.x << 2) + (threadIdx.x >> 6);
    if (g >= G) return;
    int lane = threadIdx.x & 63;
    const float2* base = (const float2*)h;
    float ax = 0.f, ay = 0.f;
    int i0 = gstart[g], i1 = gstart[g + 1];
    for (int i = i0; i < i1; ++i) {
        float2 v = base[i * 64 + lane];
        ax += v.x; ay += v.y;
    }
    pooled[g * 128 + lane * 2] = ax;
    pooled[g * 128 + lane * 2 + 1] = ay;
}

__global__ void pool_stats(const float* __restrict__ pooled, const float* __restrict__ bn_g,
                           const float* __restrict__ bn_b, float* __restrict__ pscale,
                           float* __restrict__ pshift, int G) {
    __shared__ float ss[8][128], sq[8][128];
    int tid = threadIdx.x;           // 1024 threads
    int c = tid & 127, seg = tid >> 7;
    int per = (G + 7) / 8;
    int g0 = seg * per;
    int g1 = g0 + per; if (g1 > G) g1 = G;
    float s = 0.f, q = 0.f;
    for (int g = g0; g < g1; ++g) { float v = pooled[g * 128 + c]; s += v; q += v * v; }
    ss[seg][c] = s; sq[seg][c] = q;
    __syncthreads();
    if (seg == 0) {
        for (int t2 = 1; t2 < 8; ++t2) { s += ss[t2][c]; q += sq[t2][c]; }
        float mu = s / (float)G;
        float var = q / (float)G - mu * mu;
        float rs = rsqrtf(var + 1e-5f);
        float sc = rs * bn_g[c];
        pscale[c] = sc;
        pshift[c] = bn_b[c] - mu * sc;
    }
}

__global__ void final_fc(const float* __restrict__ pooled, const float* __restrict__ pscale,
                         const float* __restrict__ pshift, const float* __restrict__ fcW,
                         const float* __restrict__ fcb, float* __restrict__ out, int total) {
    int idx = blockIdx.x * 256 + threadIdx.x;
    if (idx >= total) return;
    int o = idx & 63, g = idx >> 6;
    float acc = fcb[o];
    const float* prow = pooled + g * 128;
#pragma unroll 4
    for (int c = 0; c < 128; ++c) {
        float z = prow[c] * pscale[c] + pshift[c];
        acc += z * fcW[c * 64 + o];
    }
    out[idx] = acc;
}

// ------------------------------ launcher ----------------------------------

extern "C" void kernel_launch(void* const* d_in, const int* in_sizes, int n_in,
                              void* d_out, int out_size, void* d_ws, size_t ws_size,
                              hipStream_t stream) {
    const float* x    = (const float*)d_in[0];
    const int*   ei   = (const int*)d_in[1];
    const int*   batch= (const int*)d_in[2];
    const float* W1s  = (const float*)d_in[3];
    const float* b1s  = (const float*)d_in[4];
    const float* g1s  = (const float*)d_in[5];
    const float* be1s = (const float*)d_in[6];
    const float* W2s  = (const float*)d_in[7];
    const float* b2s  = (const float*)d_in[8];
    const float* bn_g = (const float*)d_in[9];
    const float* bn_b = (const float*)d_in[10];
    const float* fcW  = (const float*)d_in[11];
    const float* fcb  = (const float*)d_in[12];
    float* out = (float*)d_out;

    const int N = in_sizes[0] / 128;
    const int E = in_sizes[1] / 2;
    const int G = out_size / 64;
    const int L = in_sizes[3] / (128 * 128);
    const int* src = ei;
    const int* dst = ei + E;

    size_t off = 0;
    auto carve = [&](size_t bytes) -> void* {
        void* p = (char*)d_ws + off;
        off += (bytes + 255) & ~(size_t)255;
        return p;
    };
    int* deg    = (int*)carve((size_t)N * 4);
    int* cur    = (int*)carve((size_t)N * 4);
    int* ofs    = (int*)carve((size_t)(N + 1) * 4);
    int* bsum   = (int*)carve(4096 * 4);
    int* csr    = (int*)carve((size_t)E * 4);
    int* gstart = (int*)carve((size_t)(G + 1) * 4);
    unsigned short* hinH = (unsigned short*)carve((size_t)N * 128 * 2);
    unsigned short* hinL = (unsigned short*)carve((size_t)N * 128 * 2);
    unsigned short* h1H  = (unsigned short*)carve((size_t)N * 128 * 2);
    unsigned short* h1L  = (unsigned short*)carve((size_t)N * 128 * 2);
    float* hbuf  = (float*)carve((size_t)N * 128 * 4);
    unsigned short* wtH = (unsigned short*)carve(16384 * 2);
    unsigned short* wtL = (unsigned short*)carve(16384 * 2);
    float* b2p    = (float*)carve(128 * 4);
    float* colsum = (float*)carve(128 * 4);
    float* colsq  = (float*)carve(128 * 4);
    float* pooled = (float*)carve((size_t)G * 128 * 4);
    float* pscale = (float*)carve(128 * 4);
    float* pshift = (float*)carve(128 * 4);
    (void)ws_size; (void)n_in;

    // ---- CSR build (once per call) ----
    zero2_kernel<<<(N + 255) / 256, 256, 0, stream>>>(deg, cur, N);
    hist_kernel<<<(E + 255) / 256, 256, 0, stream>>>(dst, deg, E);
    int nb1 = (N + 255) / 256;
    scan1_kernel<<<nb1, 256, 0, stream>>>(deg, ofs, bsum, N);
    scan2_kernel<<<1, 1024, 0, stream>>>(bsum, nb1);
    scan3_kernel<<<nb1, 256, 0, stream>>>(ofs, bsum, N, E);
    fill_kernel<<<(E + 255) / 256, 256, 0, stream>>>(src, dst, ofs, cur, csr, E);

    // ---- layers ----
    const float* hprev = x;
    int gemmBlocks = (N + 127) / 128;
    for (int l = 0; l < L; ++l) {
        agg_split<<<(N + 3) / 4, 256, 0, stream>>>(hprev, ofs, csr, hinH, hinL, N);
        prep_w1<<<64, 256, 0, stream>>>(W1s + (size_t)l * 16384, wtH, wtL, colsum, colsq);
        gemm_split<1><<<gemmBlocks, 256, 0, stream>>>(hinH, hinL, wtH, wtL, b1s + l * 128,
                                                      h1H, h1L, nullptr, colsum, colsq, N);
        prep_w2<<<1, 256, 0, stream>>>(W2s + (size_t)l * 16384, b2s + l * 128, g1s + l * 128,
                                       be1s + l * 128, colsum, colsq, wtH, wtL, b2p, N);
        gemm_split<2><<<gemmBlocks, 256, 0, stream>>>(h1H, h1L, wtH, wtL, b2p,
                                                      nullptr, nullptr, hbuf, nullptr, nullptr, N);
        hprev = hbuf;
    }

    // ---- readout ----
    graph_bounds<<<(N + 255) / 256, 256, 0, stream>>>(batch, gstart, N, G);
    pool_kernel<<<(G + 3) / 4, 256, 0, stream>>>(hbuf, gstart, pooled, G);
    pool_stats<<<1, 1024, 0, stream>>>(pooled, bn_g, bn_b, pscale, pshift, G);
    final_fc<<<(G * 64 + 255) / 256, 256, 0, stream>>>(pooled, pscale, pshift, fcW, fcb,
                                                       out, G * 64);
}

// Round 4
// 1040.934 us; speedup vs baseline: 1.1738x; 1.1738x over previous
//
#include <hip/hip_runtime.h>

// ---------------------------------------------------------------------------
// GIN forward on MI355X.
//   CSR build (zero, hist, scan x3, fill)
//   per layer: agg (half-wave/node, float4, unroll-8) -> bf16 hi/lo split
//              prep_w1 (W1 -> transposed bf16 hi/lo, zero col stats)
//              gemm<1> (split-bf16 MFMA, bias+leaky, writes h1 hi/lo + col stats)
//              bn_fold (stats -> s,t + b2')  + w2t (fold BN into W2 hi/lo)
//              gemm<2> (split-bf16 MFMA, bias+leaky, writes fp32 hbuf)
//   graph_bounds, pool, pool_stats, final_fc
// ---------------------------------------------------------------------------

typedef __attribute__((ext_vector_type(8))) __bf16 bf16x8;
typedef __attribute__((ext_vector_type(4))) float  f32x4;

__device__ __forceinline__ unsigned short f2bf(float f) {
    union { float f; unsigned int u; } v; v.f = f;
    unsigned int r = v.u + 0x7fffu + ((v.u >> 16) & 1u);
    return (unsigned short)(r >> 16);
}
__device__ __forceinline__ float bf2f(unsigned short h) {
    union { unsigned int u; float f; } v; v.u = ((unsigned int)h) << 16;
    return v.f;
}

// ------------------------------ CSR build ---------------------------------

__global__ void zero2_kernel(int* __restrict__ a, int* __restrict__ b, int n) {
    int i = blockIdx.x * 256 + threadIdx.x;
    if (i < n) { a[i] = 0; b[i] = 0; }
}

__global__ void hist_kernel(const int* __restrict__ dst, int* __restrict__ deg, int E) {
    int e = blockIdx.x * 256 + threadIdx.x;
    if (e < E) atomicAdd(&deg[dst[e]], 1);
}

__global__ void scan1_kernel(const int* __restrict__ deg, int* __restrict__ ofs,
                             int* __restrict__ bsum, int n) {
    __shared__ int sh[256];
    int tid = threadIdx.x;
    int i = blockIdx.x * 256 + tid;
    int v = (i < n) ? deg[i] : 0;
    sh[tid] = v;
    __syncthreads();
    for (int o = 1; o < 256; o <<= 1) {
        int tmp = (tid >= o) ? sh[tid - o] : 0;
        __syncthreads();
        sh[tid] += tmp;
        __syncthreads();
    }
    if (i < n) ofs[i] = sh[tid] - v;           // exclusive within block
    if (tid == 255) bsum[blockIdx.x] = sh[255];
}

__global__ void scan2_kernel(int* __restrict__ bsum, int nb) {
    __shared__ int sh[1024];
    int tid = threadIdx.x;
    int v = (tid < nb) ? bsum[tid] : 0;
    sh[tid] = v;
    __syncthreads();
    for (int o = 1; o < 1024; o <<= 1) {
        int tmp = (tid >= o) ? sh[tid - o] : 0;
        __syncthreads();
        sh[tid] += tmp;
        __syncthreads();
    }
    if (tid < nb) bsum[tid] = sh[tid] - v;     // exclusive
}

__global__ void scan3_kernel(int* __restrict__ ofs, const int* __restrict__ bsum,
                             int n, int Etot) {
    int i = blockIdx.x * 256 + threadIdx.x;
    if (i < n) ofs[i] += bsum[blockIdx.x];
    if (i == 0) ofs[n] = Etot;
}

__global__ void fill_kernel(const int* __restrict__ src, const int* __restrict__ dst,
                            const int* __restrict__ ofs, int* __restrict__ cur,
                            int* __restrict__ csr, int E) {
    int e = blockIdx.x * 256 + threadIdx.x;
    if (e >= E) return;
    int d = dst[e];
    int p = atomicAdd(&cur[d], 1);
    csr[ofs[d] + p] = src[e];
}

// --------------------------- aggregation ----------------------------------
// Half-wave (32 lanes) per node, float4 loads (one 512B row per instr),
// unroll-8 so 8 row-loads are in flight per half-wave before any accumulate.

__global__ void agg_split(const float* __restrict__ h, const int* __restrict__ ofs,
                          const int* __restrict__ csr,
                          unsigned short* __restrict__ Ohi, unsigned short* __restrict__ Olo,
                          int n) {
    int node = blockIdx.x * 8 + (threadIdx.x >> 5);
    if (node >= n) return;
    int lane = threadIdx.x & 31;
    const float4* base = (const float4*)h;
    float4 a = base[node * 32 + lane];
    float ax = a.x, ay = a.y, az = a.z, aw = a.w;
    int e0 = ofs[node], e1 = ofs[node + 1];
    int j = e0;
    for (; j + 8 <= e1; j += 8) {
        int s0 = csr[j], s1 = csr[j + 1], s2 = csr[j + 2], s3 = csr[j + 3];
        int s4 = csr[j + 4], s5 = csr[j + 5], s6 = csr[j + 6], s7 = csr[j + 7];
        float4 v0 = base[s0 * 32 + lane];
        float4 v1 = base[s1 * 32 + lane];
        float4 v2 = base[s2 * 32 + lane];
        float4 v3 = base[s3 * 32 + lane];
        float4 v4 = base[s4 * 32 + lane];
        float4 v5 = base[s5 * 32 + lane];
        float4 v6 = base[s6 * 32 + lane];
        float4 v7 = base[s7 * 32 + lane];
        ax += ((v0.x + v1.x) + (v2.x + v3.x)) + ((v4.x + v5.x) + (v6.x + v7.x));
        ay += ((v0.y + v1.y) + (v2.y + v3.y)) + ((v4.y + v5.y) + (v6.y + v7.y));
        az += ((v0.z + v1.z) + (v2.z + v3.z)) + ((v4.z + v5.z) + (v6.z + v7.z));
        aw += ((v0.w + v1.w) + (v2.w + v3.w)) + ((v4.w + v5.w) + (v6.w + v7.w));
    }
    for (; j + 4 <= e1; j += 4) {
        int s0 = csr[j], s1 = csr[j + 1], s2 = csr[j + 2], s3 = csr[j + 3];
        float4 v0 = base[s0 * 32 + lane];
        float4 v1 = base[s1 * 32 + lane];
        float4 v2 = base[s2 * 32 + lane];
        float4 v3 = base[s3 * 32 + lane];
        ax += (v0.x + v1.x) + (v2.x + v3.x);
        ay += (v0.y + v1.y) + (v2.y + v3.y);
        az += (v0.z + v1.z) + (v2.z + v3.z);
        aw += (v0.w + v1.w) + (v2.w + v3.w);
    }
    for (; j < e1; ++j) {
        float4 v = base[csr[j] * 32 + lane];
        ax += v.x; ay += v.y; az += v.z; aw += v.w;
    }
    // split to bf16 hi/lo; lane covers cols [lane*4, lane*4+4)
    unsigned short h0 = f2bf(ax), h1 = f2bf(ay), h2 = f2bf(az), h3 = f2bf(aw);
    unsigned short l0 = f2bf(ax - bf2f(h0)), l1 = f2bf(ay - bf2f(h1));
    unsigned short l2 = f2bf(az - bf2f(h2)), l3 = f2bf(aw - bf2f(h3));
    ushort4 ph = {h0, h1, h2, h3};
    ushort4 pl = {l0, l1, l2, l3};
    *(ushort4*)(Ohi + node * 128 + lane * 4) = ph;
    *(ushort4*)(Olo + node * 128 + lane * 4) = pl;
}

// --------------------------- weight prep ----------------------------------
// W [128k][128n] fp32 -> Bt hi/lo [128n][128k] bf16 (transposed). Also zero stats.

__global__ void prep_w1(const float* __restrict__ W, unsigned short* __restrict__ Bth,
                        unsigned short* __restrict__ Btl, float* __restrict__ colsum,
                        float* __restrict__ colsq) {
    int t = blockIdx.x * 256 + threadIdx.x;   // 64 blocks * 256 = 16384
    int n = t >> 7, k = t & 127;
    float v = W[k * 128 + n];
    unsigned short h = f2bf(v);
    Bth[t] = h;
    Btl[t] = f2bf(v - bf2f(h));
    if (blockIdx.x == 0 && threadIdx.x < 128) { colsum[threadIdx.x] = 0.f; colsq[threadIdx.x] = 0.f; }
}

// BN fold: s = g*rsqrt(var), t = be - mu*s ; b2'[n] = b2[n] + sum_k t[k]*W2[k][n]
__global__ void bn_fold(const float* __restrict__ W2, const float* __restrict__ b2,
                        const float* __restrict__ g1, const float* __restrict__ be1,
                        const float* __restrict__ colsum, const float* __restrict__ colsq,
                        float* __restrict__ sfold, float* __restrict__ b2p, int nrows) {
    __shared__ float tt[128];
    __shared__ float part[2][128];
    int tid = threadIdx.x;          // 256 threads
    if (tid < 128) {
        float mu = colsum[tid] / (float)nrows;
        float var = colsq[tid] / (float)nrows - mu * mu;
        float rs = rsqrtf(var + 1e-5f);
        float sc = rs * g1[tid];
        sfold[tid] = sc;
        tt[tid] = be1[tid] - mu * sc;
    }
    __syncthreads();
    int nn = tid & 127, half = tid >> 7;
    float acc = 0.f;
    for (int k = half * 64; k < half * 64 + 64; ++k)
        acc += tt[k] * W2[k * 128 + nn];
    part[half][nn] = acc;
    __syncthreads();
    if (tid < 128) b2p[tid] = b2[tid] + part[0][tid] + part[1][tid];
}

// W2'[k][n] = s[k]*W2[k][n] -> transposed bf16 hi/lo
__global__ void w2t_kernel(const float* __restrict__ W2, const float* __restrict__ sfold,
                           unsigned short* __restrict__ Bth, unsigned short* __restrict__ Btl) {
    int t = blockIdx.x * 256 + threadIdx.x;   // 64 blocks * 256 = 16384
    int n = t >> 7, k = t & 127;
    float v = sfold[k] * W2[k * 128 + n];
    unsigned short h = f2bf(v);
    Bth[t] = h;
    Btl[t] = f2bf(v - bf2f(h));
}

// ------------------------------- GEMM -------------------------------------
// C[N,128] = A[N,128] @ B[128,128], split-bf16 (Ah Bh + Ah Bl + Al Bh), MFMA 16x16x32.
// Block: 256 threads (4 waves). Wave w owns cols [w*32, w*32+32), block owns 128 rows.

template <int STAGE>
__global__ void gemm_split(const unsigned short* __restrict__ Ah, const unsigned short* __restrict__ Al,
                           const unsigned short* __restrict__ Bh, const unsigned short* __restrict__ Bl,
                           const float* __restrict__ bias,
                           unsigned short* __restrict__ Ohi, unsigned short* __restrict__ Olo,
                           float* __restrict__ Of32,
                           float* __restrict__ colsum, float* __restrict__ colsq,
                           int nrows) {
    const int lane = threadIdx.x & 63;
    const int wv = threadIdx.x >> 6;
    const int l15 = lane & 15;
    const int lg = lane >> 4;          // 0..3
    const int colbase = wv * 32;
    const int rowbase = blockIdx.x * 128;

    bf16x8 bh[2][4], bl[2][4];
#pragma unroll
    for (int nc = 0; nc < 2; ++nc)
#pragma unroll
        for (int ks = 0; ks < 4; ++ks) {
            int n = colbase + nc * 16 + l15;
            int k = ks * 32 + lg * 8;
            bh[nc][ks] = *(const bf16x8*)(Bh + n * 128 + k);
            bl[nc][ks] = *(const bf16x8*)(Bl + n * 128 + k);
        }
    float bias0 = bias[colbase + l15];
    float bias1 = bias[colbase + 16 + l15];
    float s0 = 0.f, s1 = 0.f, q0 = 0.f, q1 = 0.f;

#pragma unroll 2
    for (int mr = 0; mr < 8; ++mr) {
        int arow = rowbase + mr * 16 + l15;
        int ar = (arow < nrows) ? arow : (nrows - 1);
        const unsigned short* pa = Ah + ar * 128 + lg * 8;
        const unsigned short* pl = Al + ar * 128 + lg * 8;
        bf16x8 ah[4], al[4];
#pragma unroll
        for (int ks = 0; ks < 4; ++ks) {
            ah[ks] = *(const bf16x8*)(pa + ks * 32);
            al[ks] = *(const bf16x8*)(pl + ks * 32);
        }
        f32x4 acc0 = {0.f, 0.f, 0.f, 0.f};
        f32x4 acc1 = {0.f, 0.f, 0.f, 0.f};
#pragma unroll
        for (int ks = 0; ks < 4; ++ks) {
            acc0 = __builtin_amdgcn_mfma_f32_16x16x32_bf16(ah[ks], bh[0][ks], acc0, 0, 0, 0);
            acc1 = __builtin_amdgcn_mfma_f32_16x16x32_bf16(ah[ks], bh[1][ks], acc1, 0, 0, 0);
            acc0 = __builtin_amdgcn_mfma_f32_16x16x32_bf16(ah[ks], bl[0][ks], acc0, 0, 0, 0);
            acc1 = __builtin_amdgcn_mfma_f32_16x16x32_bf16(ah[ks], bl[1][ks], acc1, 0, 0, 0);
            acc0 = __builtin_amdgcn_mfma_f32_16x16x32_bf16(al[ks], bh[0][ks], acc0, 0, 0, 0);
            acc1 = __builtin_amdgcn_mfma_f32_16x16x32_bf16(al[ks], bh[1][ks], acc1, 0, 0, 0);
        }
        int orow0 = rowbase + mr * 16 + lg * 4;
#pragma unroll
        for (int r = 0; r < 4; ++r) {
            int orow = orow0 + r;
            if (orow < nrows) {
                float v0 = acc0[r] + bias0;
                v0 = v0 > 0.f ? v0 : 0.2f * v0;
                float v1 = acc1[r] + bias1;
                v1 = v1 > 0.f ? v1 : 0.2f * v1;
                int c0 = colbase + l15;
                int c1 = colbase + 16 + l15;
                if (STAGE == 1) {
                    unsigned short h0 = f2bf(v0);
                    Ohi[orow * 128 + c0] = h0;
                    Olo[orow * 128 + c0] = f2bf(v0 - bf2f(h0));
                    unsigned short h1 = f2bf(v1);
                    Ohi[orow * 128 + c1] = h1;
                    Olo[orow * 128 + c1] = f2bf(v1 - bf2f(h1));
                    s0 += v0; q0 += v0 * v0;
                    s1 += v1; q1 += v1 * v1;
                } else {
                    Of32[orow * 128 + c0] = v0;
                    Of32[orow * 128 + c1] = v1;
                }
            }
        }
    }
    if (STAGE == 1) {
        s0 += __shfl_xor(s0, 16); s0 += __shfl_xor(s0, 32);
        q0 += __shfl_xor(q0, 16); q0 += __shfl_xor(q0, 32);
        s1 += __shfl_xor(s1, 16); s1 += __shfl_xor(s1, 32);
        q1 += __shfl_xor(q1, 16); q1 += __shfl_xor(q1, 32);
        if (lg == 0) {
            atomicAdd(&colsum[colbase + l15], s0);
            atomicAdd(&colsq[colbase + l15], q0);
            atomicAdd(&colsum[colbase + 16 + l15], s1);
            atomicAdd(&colsq[colbase + 16 + l15], q1);
        }
    }
}

// ------------------------------ pooling -----------------------------------

__global__ void graph_bounds(const int* __restrict__ batch, int* __restrict__ gstart,
                             int n, int G) {
    int i = blockIdx.x * 256 + threadIdx.x;
    if (i >= n) return;
    int b = batch[i];
    if (i == 0) {
        for (int x = 0; x <= b; ++x) gstart[x] = 0;
    } else {
        int p = batch[i - 1];
        for (int x = p + 1; x <= b; ++x) gstart[x] = i;
    }
    if (i == n - 1) {
        for (int x = b + 1; x <= G; ++x) gstart[x] = n;
    }
}

__global__ void pool_kernel(const float* __restrict__ h, const int* __restrict__ gstart,
                            float* __restrict__ pooled, int G) {
    int g = blockIdx.x * 8 + (threadIdx.x >> 5);
    if (g >= G) return;
    int lane = threadIdx.x & 31;
    const float4* base = (const float4*)h;
    float ax = 0.f, ay = 0.f, az = 0.f, aw = 0.f;
    int i0 = gstart[g], i1 = gstart[g + 1];
    for (int i = i0; i < i1; ++i) {
        float4 v = base[i * 32 + lane];
        ax += v.x; ay += v.y; az += v.z; aw += v.w;
    }
    float4 o = {ax, ay, az, aw};
    *(float4*)(pooled + g * 128 + lane * 4) = o;
}

__global__ void pool_stats(const float* __restrict__ pooled, const float* __restrict__ bn_g,
                           const float* __restrict__ bn_b, float* __restrict__ pscale,
                           float* __restrict__ pshift, int G) {
    __shared__ float ss[8][128], sq[8][128];
    int tid = threadIdx.x;           // 1024 threads
    int c = tid & 127, seg = tid >> 7;
    int per = (G + 7) / 8;
    int g0 = seg * per;
    int g1 = g0 + per; if (g1 > G) g1 = G;
    float s = 0.f, q = 0.f;
    for (int g = g0; g < g1; ++g) { float v = pooled[g * 128 + c]; s += v; q += v * v; }
    ss[seg][c] = s; sq[seg][c] = q;
    __syncthreads();
    if (seg == 0) {
        for (int t2 = 1; t2 < 8; ++t2) { s += ss[t2][c]; q += sq[t2][c]; }
        float mu = s / (float)G;
        float var = q / (float)G - mu * mu;
        float rs = rsqrtf(var + 1e-5f);
        float sc = rs * bn_g[c];
        pscale[c] = sc;
        pshift[c] = bn_b[c] - mu * sc;
    }
}

__global__ void final_fc(const float* __restrict__ pooled, const float* __restrict__ pscale,
                         const float* __restrict__ pshift, const float* __restrict__ fcW,
                         const float* __restrict__ fcb, float* __restrict__ out, int total) {
    int idx = blockIdx.x * 256 + threadIdx.x;
    if (idx >= total) return;
    int o = idx & 63, g = idx >> 6;
    float acc = fcb[o];
    const float* prow = pooled + g * 128;
#pragma unroll 4
    for (int c = 0; c < 128; ++c) {
        float z = prow[c] * pscale[c] + pshift[c];
        acc += z * fcW[c * 64 + o];
    }
    out[idx] = acc;
}

// ------------------------------ launcher ----------------------------------

extern "C" void kernel_launch(void* const* d_in, const int* in_sizes, int n_in,
                              void* d_out, int out_size, void* d_ws, size_t ws_size,
                              hipStream_t stream) {
    const float* x    = (const float*)d_in[0];
    const int*   ei   = (const int*)d_in[1];
    const int*   batch= (const int*)d_in[2];
    const float* W1s  = (const float*)d_in[3];
    const float* b1s  = (const float*)d_in[4];
    const float* g1s  = (const float*)d_in[5];
    const float* be1s = (const float*)d_in[6];
    const float* W2s  = (const float*)d_in[7];
    const float* b2s  = (const float*)d_in[8];
    const float* bn_g = (const float*)d_in[9];
    const float* bn_b = (const float*)d_in[10];
    const float* fcW  = (const float*)d_in[11];
    const float* fcb  = (const float*)d_in[12];
    float* out = (float*)d_out;

    const int N = in_sizes[0] / 128;
    const int E = in_sizes[1] / 2;
    const int G = out_size / 64;
    const int L = in_sizes[3] / (128 * 128);
    const int* src = ei;
    const int* dst = ei + E;

    size_t off = 0;
    auto carve = [&](size_t bytes) -> void* {
        void* p = (char*)d_ws + off;
        off += (bytes + 255) & ~(size_t)255;
        return p;
    };
    int* deg    = (int*)carve((size_t)N * 4);
    int* cur    = (int*)carve((size_t)N * 4);
    int* ofs    = (int*)carve((size_t)(N + 1) * 4);
    int* bsum   = (int*)carve(4096 * 4);
    int* csr    = (int*)carve((size_t)E * 4);
    int* gstart = (int*)carve((size_t)(G + 1) * 4);
    unsigned short* hinH = (unsigned short*)carve((size_t)N * 128 * 2);
    unsigned short* hinL = (unsigned short*)carve((size_t)N * 128 * 2);
    unsigned short* h1H  = (unsigned short*)carve((size_t)N * 128 * 2);
    unsigned short* h1L  = (unsigned short*)carve((size_t)N * 128 * 2);
    float* hbuf  = (float*)carve((size_t)N * 128 * 4);
    unsigned short* wtH = (unsigned short*)carve(16384 * 2);
    unsigned short* wtL = (unsigned short*)carve(16384 * 2);
    float* b2p    = (float*)carve(128 * 4);
    float* sfold  = (float*)carve(128 * 4);
    float* colsum = (float*)carve(128 * 4);
    float* colsq  = (float*)carve(128 * 4);
    float* pooled = (float*)carve((size_t)G * 128 * 4);
    float* pscale = (float*)carve(128 * 4);
    float* pshift = (float*)carve(128 * 4);
    (void)ws_size; (void)n_in;

    // ---- CSR build (once per call) ----
    zero2_kernel<<<(N + 255) / 256, 256, 0, stream>>>(deg, cur, N);
    hist_kernel<<<(E + 255) / 256, 256, 0, stream>>>(dst, deg, E);
    int nb1 = (N + 255) / 256;
    scan1_kernel<<<nb1, 256, 0, stream>>>(deg, ofs, bsum, N);
    scan2_kernel<<<1, 1024, 0, stream>>>(bsum, nb1);
    scan3_kernel<<<nb1, 256, 0, stream>>>(ofs, bsum, N, E);
    fill_kernel<<<(E + 255) / 256, 256, 0, stream>>>(src, dst, ofs, cur, csr, E);

    // ---- layers ----
    const float* hprev = x;
    int gemmBlocks = (N + 127) / 128;
    for (int l = 0; l < L; ++l) {
        agg_split<<<(N + 7) / 8, 256, 0, stream>>>(hprev, ofs, csr, hinH, hinL, N);
        prep_w1<<<64, 256, 0, stream>>>(W1s + (size_t)l * 16384, wtH, wtL, colsum, colsq);
        gemm_split<1><<<gemmBlocks, 256, 0, stream>>>(hinH, hinL, wtH, wtL, b1s + l * 128,
                                                      h1H, h1L, nullptr, colsum, colsq, N);
        bn_fold<<<1, 256, 0, stream>>>(W2s + (size_t)l * 16384, b2s + l * 128, g1s + l * 128,
                                       be1s + l * 128, colsum, colsq, sfold, b2p, N);
        w2t_kernel<<<64, 256, 0, stream>>>(W2s + (size_t)l * 16384, sfold, wtH, wtL);
        gemm_split<2><<<gemmBlocks, 256, 0, stream>>>(h1H, h1L, wtH, wtL, b2p,
                                                      nullptr, nullptr, hbuf, nullptr, nullptr, N);
        hprev = hbuf;
    }

    // ---- readout ----
    graph_bounds<<<(N + 255) / 256, 256, 0, stream>>>(batch, gstart, N, G);
    pool_kernel<<<(G + 7) / 8, 256, 0, stream>>>(hbuf, gstart, pooled, G);
    pool_stats<<<1, 1024, 0, stream>>>(pooled, bn_g, bn_b, pscale, pshift, G);
    final_fc<<<(G * 64 + 255) / 256, 256, 0, stream>>>(pooled, pscale, pshift, fcW, fcb,
                                                       out, G * 64);
}

// Round 5
// 1030.736 us; speedup vs baseline: 1.1854x; 1.0099x over previous
//
#include <hip/hip_runtime.h>

// ---------------------------------------------------------------------------
// GIN forward on MI355X.
//   prep_w1_all (all L layers W1 -> transposed bf16 hi/lo, once)
//   CSR build (zero, hist, scan x3, fill)
//   per layer: agg (half-wave/node, float4, 16-deep pipeline; block0 zeroes stats)
//              gemm<1> (split-bf16 MFMA, bias+leaky, writes h1 hi/lo + col stats)
//              w2t_fold (BN fold + W2 transform + b2' in one kernel)
//              gemm<2> (split-bf16 MFMA, bias+leaky, writes fp32 hbuf)
//   graph_bounds, pool, pool_stats, final_fc
// ---------------------------------------------------------------------------

typedef __attribute__((ext_vector_type(8))) __bf16 bf16x8;
typedef __attribute__((ext_vector_type(4))) float  f32x4;

__device__ __forceinline__ unsigned short f2bf(float f) {
    union { float f; unsigned int u; } v; v.f = f;
    unsigned int r = v.u + 0x7fffu + ((v.u >> 16) & 1u);
    return (unsigned short)(r >> 16);
}
__device__ __forceinline__ float bf2f(unsigned short h) {
    union { unsigned int u; float f; } v; v.u = ((unsigned int)h) << 16;
    return v.f;
}

// ------------------------------ CSR build ---------------------------------

__global__ void zero2_kernel(int* __restrict__ a, int* __restrict__ b, int n) {
    int i = blockIdx.x * 256 + threadIdx.x;
    if (i < n) { a[i] = 0; b[i] = 0; }
}

__global__ void hist_kernel(const int* __restrict__ dst, int* __restrict__ deg, int E) {
    int e = blockIdx.x * 256 + threadIdx.x;
    if (e < E) atomicAdd(&deg[dst[e]], 1);
}

__global__ void scan1_kernel(const int* __restrict__ deg, int* __restrict__ ofs,
                             int* __restrict__ bsum, int n) {
    __shared__ int sh[256];
    int tid = threadIdx.x;
    int i = blockIdx.x * 256 + tid;
    int v = (i < n) ? deg[i] : 0;
    sh[tid] = v;
    __syncthreads();
    for (int o = 1; o < 256; o <<= 1) {
        int tmp = (tid >= o) ? sh[tid - o] : 0;
        __syncthreads();
        sh[tid] += tmp;
        __syncthreads();
    }
    if (i < n) ofs[i] = sh[tid] - v;           // exclusive within block
    if (tid == 255) bsum[blockIdx.x] = sh[255];
}

__global__ void scan2_kernel(int* __restrict__ bsum, int nb) {
    __shared__ int sh[1024];
    int tid = threadIdx.x;
    int v = (tid < nb) ? bsum[tid] : 0;
    sh[tid] = v;
    __syncthreads();
    for (int o = 1; o < 1024; o <<= 1) {
        int tmp = (tid >= o) ? sh[tid - o] : 0;
        __syncthreads();
        sh[tid] += tmp;
        __syncthreads();
    }
    if (tid < nb) bsum[tid] = sh[tid] - v;     // exclusive
}

__global__ void scan3_kernel(int* __restrict__ ofs, const int* __restrict__ bsum,
                             int n, int Etot) {
    int i = blockIdx.x * 256 + threadIdx.x;
    if (i < n) ofs[i] += bsum[blockIdx.x];
    if (i == 0) ofs[n] = Etot;
}

__global__ void fill_kernel(const int* __restrict__ src, const int* __restrict__ dst,
                            const int* __restrict__ ofs, int* __restrict__ cur,
                            int* __restrict__ csr, int E) {
    int e = blockIdx.x * 256 + threadIdx.x;
    if (e >= E) return;
    int d = dst[e];
    int p = atomicAdd(&cur[d], 1);
    csr[ofs[d] + p] = src[e];
}

// --------------------------- aggregation ----------------------------------
// Half-wave (32 lanes) per node, float4 loads (one 512B row per instr),
// 16-deep load pipeline. Block 0 additionally zeroes the col stats for the
// following gemm<1> (safe: stream-ordered before gemm<1> launches).

__global__ void agg_split(const float* __restrict__ h, const int* __restrict__ ofs,
                          const int* __restrict__ csr,
                          unsigned short* __restrict__ Ohi, unsigned short* __restrict__ Olo,
                          float* __restrict__ colsum, float* __restrict__ colsq,
                          int n) {
    if (blockIdx.x == 0) {
        if (threadIdx.x < 128) colsum[threadIdx.x] = 0.f;
        else colsq[threadIdx.x - 128] = 0.f;
    }
    int node = blockIdx.x * 8 + (threadIdx.x >> 5);
    if (node >= n) return;
    int lane = threadIdx.x & 31;
    const float4* base = (const float4*)h;
    float4 a = base[node * 32 + lane];
    float ax = a.x, ay = a.y, az = a.z, aw = a.w;
    int e0 = ofs[node], e1 = ofs[node + 1];
    int j = e0;
    for (; j + 16 <= e1; j += 16) {
        int s[16];
#pragma unroll
        for (int u = 0; u < 16; ++u) s[u] = csr[j + u];
        float4 v[16];
#pragma unroll
        for (int u = 0; u < 16; ++u) v[u] = base[s[u] * 32 + lane];
        float bx0 = 0.f, by0 = 0.f, bz0 = 0.f, bw0 = 0.f;
        float bx1 = 0.f, by1 = 0.f, bz1 = 0.f, bw1 = 0.f;
#pragma unroll
        for (int u = 0; u < 16; u += 2) {
            bx0 += v[u].x; by0 += v[u].y; bz0 += v[u].z; bw0 += v[u].w;
            bx1 += v[u + 1].x; by1 += v[u + 1].y; bz1 += v[u + 1].z; bw1 += v[u + 1].w;
        }
        ax += bx0 + bx1; ay += by0 + by1; az += bz0 + bz1; aw += bw0 + bw1;
    }
    for (; j + 8 <= e1; j += 8) {
        int s[8];
#pragma unroll
        for (int u = 0; u < 8; ++u) s[u] = csr[j + u];
        float4 v[8];
#pragma unroll
        for (int u = 0; u < 8; ++u) v[u] = base[s[u] * 32 + lane];
#pragma unroll
        for (int u = 0; u < 8; ++u) {
            ax += v[u].x; ay += v[u].y; az += v[u].z; aw += v[u].w;
        }
    }
    for (; j + 4 <= e1; j += 4) {
        int s0 = csr[j], s1 = csr[j + 1], s2 = csr[j + 2], s3 = csr[j + 3];
        float4 v0 = base[s0 * 32 + lane];
        float4 v1 = base[s1 * 32 + lane];
        float4 v2 = base[s2 * 32 + lane];
        float4 v3 = base[s3 * 32 + lane];
        ax += (v0.x + v1.x) + (v2.x + v3.x);
        ay += (v0.y + v1.y) + (v2.y + v3.y);
        az += (v0.z + v1.z) + (v2.z + v3.z);
        aw += (v0.w + v1.w) + (v2.w + v3.w);
    }
    for (; j < e1; ++j) {
        float4 v = base[csr[j] * 32 + lane];
        ax += v.x; ay += v.y; az += v.z; aw += v.w;
    }
    // split to bf16 hi/lo; lane covers cols [lane*4, lane*4+4)
    unsigned short h0 = f2bf(ax), h1 = f2bf(ay), h2 = f2bf(az), h3 = f2bf(aw);
    unsigned short l0 = f2bf(ax - bf2f(h0)), l1 = f2bf(ay - bf2f(h1));
    unsigned short l2 = f2bf(az - bf2f(h2)), l3 = f2bf(aw - bf2f(h3));
    ushort4 ph = {h0, h1, h2, h3};
    ushort4 pl = {l0, l1, l2, l3};
    *(ushort4*)(Ohi + node * 128 + lane * 4) = ph;
    *(ushort4*)(Olo + node * 128 + lane * 4) = pl;
}

// --------------------------- weight prep ----------------------------------
// All L layers at once: W1s[l][k][n] fp32 -> Bt[l][n][k] bf16 hi/lo.

__global__ void prep_w1_all(const float* __restrict__ W1s, unsigned short* __restrict__ Bth,
                            unsigned short* __restrict__ Btl, int total) {
    int t = blockIdx.x * 256 + threadIdx.x;   // total = L*16384
    if (t >= total) return;
    int lbase = t & ~16383;                   // layer offset
    int r = t & 16383;
    int n = r >> 7, k = r & 127;
    float v = W1s[lbase + k * 128 + n];
    unsigned short h = f2bf(v);
    Bth[t] = h;
    Btl[t] = f2bf(v - bf2f(h));
}

// BN fold + W2 transform + b2' in one kernel (64 blocks).
// Every block recomputes s[k], tt[k] (cheap); block 0 also produces b2p.
__global__ void w2t_fold(const float* __restrict__ W2, const float* __restrict__ b2,
                         const float* __restrict__ g1, const float* __restrict__ be1,
                         const float* __restrict__ colsum, const float* __restrict__ colsq,
                         unsigned short* __restrict__ Bth, unsigned short* __restrict__ Btl,
                         float* __restrict__ b2p, int nrows) {
    __shared__ float s[128], tt[128];
    int tid = threadIdx.x;          // 256 threads
    if (tid < 128) {
        float mu = colsum[tid] / (float)nrows;
        float var = colsq[tid] / (float)nrows - mu * mu;
        float rs = rsqrtf(var + 1e-5f);
        float sc = rs * g1[tid];
        s[tid] = sc;
        tt[tid] = be1[tid] - mu * sc;
    }
    __syncthreads();
    int t = blockIdx.x * 256 + tid;           // 64 blocks * 256 = 16384
    int n = t >> 7, k = t & 127;
    float v = s[k] * W2[k * 128 + n];
    unsigned short h = f2bf(v);
    Bth[t] = h;
    Btl[t] = f2bf(v - bf2f(h));
    if (blockIdx.x == 0) {
        __shared__ float part[2][128];
        int nn = tid & 127, half = tid >> 7;
        float acc = 0.f;
        for (int kk = half * 64; kk < half * 64 + 64; ++kk)
            acc += tt[kk] * W2[kk * 128 + nn];
        part[half][nn] = acc;
        __syncthreads();
        if (tid < 128) b2p[tid] = b2[tid] + part[0][tid] + part[1][tid];
    }
}

// ------------------------------- GEMM -------------------------------------
// C[N,128] = A[N,128] @ B[128,128], split-bf16 (Ah Bh + Ah Bl + Al Bh), MFMA 16x16x32.
// Block: 256 threads (4 waves). Wave w owns cols [w*32, w*32+32), block owns 128 rows.

template <int STAGE>
__global__ void gemm_split(const unsigned short* __restrict__ Ah, const unsigned short* __restrict__ Al,
                           const unsigned short* __restrict__ Bh, const unsigned short* __restrict__ Bl,
                           const float* __restrict__ bias,
                           unsigned short* __restrict__ Ohi, unsigned short* __restrict__ Olo,
                           float* __restrict__ Of32,
                           float* __restrict__ colsum, float* __restrict__ colsq,
                           int nrows) {
    const int lane = threadIdx.x & 63;
    const int wv = threadIdx.x >> 6;
    const int l15 = lane & 15;
    const int lg = lane >> 4;          // 0..3
    const int colbase = wv * 32;
    const int rowbase = blockIdx.x * 128;

    bf16x8 bh[2][4], bl[2][4];
#pragma unroll
    for (int nc = 0; nc < 2; ++nc)
#pragma unroll
        for (int ks = 0; ks < 4; ++ks) {
            int n = colbase + nc * 16 + l15;
            int k = ks * 32 + lg * 8;
            bh[nc][ks] = *(const bf16x8*)(Bh + n * 128 + k);
            bl[nc][ks] = *(const bf16x8*)(Bl + n * 128 + k);
        }
    float bias0 = bias[colbase + l15];
    float bias1 = bias[colbase + 16 + l15];
    float s0 = 0.f, s1 = 0.f, q0 = 0.f, q1 = 0.f;

#pragma unroll 2
    for (int mr = 0; mr < 8; ++mr) {
        int arow = rowbase + mr * 16 + l15;
        int ar = (arow < nrows) ? arow : (nrows - 1);
        const unsigned short* pa = Ah + ar * 128 + lg * 8;
        const unsigned short* pl = Al + ar * 128 + lg * 8;
        bf16x8 ah[4], al[4];
#pragma unroll
        for (int ks = 0; ks < 4; ++ks) {
            ah[ks] = *(const bf16x8*)(pa + ks * 32);
            al[ks] = *(const bf16x8*)(pl + ks * 32);
        }
        f32x4 acc0 = {0.f, 0.f, 0.f, 0.f};
        f32x4 acc1 = {0.f, 0.f, 0.f, 0.f};
#pragma unroll
        for (int ks = 0; ks < 4; ++ks) {
            acc0 = __builtin_amdgcn_mfma_f32_16x16x32_bf16(ah[ks], bh[0][ks], acc0, 0, 0, 0);
            acc1 = __builtin_amdgcn_mfma_f32_16x16x32_bf16(ah[ks], bh[1][ks], acc1, 0, 0, 0);
            acc0 = __builtin_amdgcn_mfma_f32_16x16x32_bf16(ah[ks], bl[0][ks], acc0, 0, 0, 0);
            acc1 = __builtin_amdgcn_mfma_f32_16x16x32_bf16(ah[ks], bl[1][ks], acc1, 0, 0, 0);
            acc0 = __builtin_amdgcn_mfma_f32_16x16x32_bf16(al[ks], bh[0][ks], acc0, 0, 0, 0);
            acc1 = __builtin_amdgcn_mfma_f32_16x16x32_bf16(al[ks], bh[1][ks], acc1, 0, 0, 0);
        }
        int orow0 = rowbase + mr * 16 + lg * 4;
#pragma unroll
        for (int r = 0; r < 4; ++r) {
            int orow = orow0 + r;
            if (orow < nrows) {
                float v0 = acc0[r] + bias0;
                v0 = v0 > 0.f ? v0 : 0.2f * v0;
                float v1 = acc1[r] + bias1;
                v1 = v1 > 0.f ? v1 : 0.2f * v1;
                int c0 = colbase + l15;
                int c1 = colbase + 16 + l15;
                if (STAGE == 1) {
                    unsigned short h0 = f2bf(v0);
                    Ohi[orow * 128 + c0] = h0;
                    Olo[orow * 128 + c0] = f2bf(v0 - bf2f(h0));
                    unsigned short h1 = f2bf(v1);
                    Ohi[orow * 128 + c1] = h1;
                    Olo[orow * 128 + c1] = f2bf(v1 - bf2f(h1));
                    s0 += v0; q0 += v0 * v0;
                    s1 += v1; q1 += v1 * v1;
                } else {
                    Of32[orow * 128 + c0] = v0;
                    Of32[orow * 128 + c1] = v1;
                }
            }
        }
    }
    if (STAGE == 1) {
        s0 += __shfl_xor(s0, 16); s0 += __shfl_xor(s0, 32);
        q0 += __shfl_xor(q0, 16); q0 += __shfl_xor(q0, 32);
        s1 += __shfl_xor(s1, 16); s1 += __shfl_xor(s1, 32);
        q1 += __shfl_xor(q1, 16); q1 += __shfl_xor(q1, 32);
        if (lg == 0) {
            atomicAdd(&colsum[colbase + l15], s0);
            atomicAdd(&colsq[colbase + l15], q0);
            atomicAdd(&colsum[colbase + 16 + l15], s1);
            atomicAdd(&colsq[colbase + 16 + l15], q1);
        }
    }
}

// ------------------------------ pooling -----------------------------------

__global__ void graph_bounds(const int* __restrict__ batch, int* __restrict__ gstart,
                             int n, int G) {
    int i = blockIdx.x * 256 + threadIdx.x;
    if (i >= n) return;
    int b = batch[i];
    if (i == 0) {
        for (int x = 0; x <= b; ++x) gstart[x] = 0;
    } else {
        int p = batch[i - 1];
        for (int x = p + 1; x <= b; ++x) gstart[x] = i;
    }
    if (i == n - 1) {
        for (int x = b + 1; x <= G; ++x) gstart[x] = n;
    }
}

__global__ void pool_kernel(const float* __restrict__ h, const int* __restrict__ gstart,
                            float* __restrict__ pooled, int G) {
    int g = blockIdx.x * 8 + (threadIdx.x >> 5);
    if (g >= G) return;
    int lane = threadIdx.x & 31;
    const float4* base = (const float4*)h;
    float ax = 0.f, ay = 0.f, az = 0.f, aw = 0.f;
    int i0 = gstart[g], i1 = gstart[g + 1];
    for (int i = i0; i < i1; ++i) {
        float4 v = base[i * 32 + lane];
        ax += v.x; ay += v.y; az += v.z; aw += v.w;
    }
    float4 o = {ax, ay, az, aw};
    *(float4*)(pooled + g * 128 + lane * 4) = o;
}

__global__ void pool_stats(const float* __restrict__ pooled, const float* __restrict__ bn_g,
                           const float* __restrict__ bn_b, float* __restrict__ pscale,
                           float* __restrict__ pshift, int G) {
    __shared__ float ss[8][128], sq[8][128];
    int tid = threadIdx.x;           // 1024 threads
    int c = tid & 127, seg = tid >> 7;
    int per = (G + 7) / 8;
    int g0 = seg * per;
    int g1 = g0 + per; if (g1 > G) g1 = G;
    float s = 0.f, q = 0.f;
    for (int g = g0; g < g1; ++g) { float v = pooled[g * 128 + c]; s += v; q += v * v; }
    ss[seg][c] = s; sq[seg][c] = q;
    __syncthreads();
    if (seg == 0) {
        for (int t2 = 1; t2 < 8; ++t2) { s += ss[t2][c]; q += sq[t2][c]; }
        float mu = s / (float)G;
        float var = q / (float)G - mu * mu;
        float rs = rsqrtf(var + 1e-5f);
        float sc = rs * bn_g[c];
        pscale[c] = sc;
        pshift[c] = bn_b[c] - mu * sc;
    }
}

__global__ void final_fc(const float* __restrict__ pooled, const float* __restrict__ pscale,
                         const float* __restrict__ pshift, const float* __restrict__ fcW,
                         const float* __restrict__ fcb, float* __restrict__ out, int total) {
    int idx = blockIdx.x * 256 + threadIdx.x;
    if (idx >= total) return;
    int o = idx & 63, g = idx >> 6;
    float acc = fcb[o];
    const float* prow = pooled + g * 128;
#pragma unroll 4
    for (int c = 0; c < 128; ++c) {
        float z = prow[c] * pscale[c] + pshift[c];
        acc += z * fcW[c * 64 + o];
    }
    out[idx] = acc;
}

// ------------------------------ launcher ----------------------------------

extern "C" void kernel_launch(void* const* d_in, const int* in_sizes, int n_in,
                              void* d_out, int out_size, void* d_ws, size_t ws_size,
                              hipStream_t stream) {
    const float* x    = (const float*)d_in[0];
    const int*   ei   = (const int*)d_in[1];
    const int*   batch= (const int*)d_in[2];
    const float* W1s  = (const float*)d_in[3];
    const float* b1s  = (const float*)d_in[4];
    const float* g1s  = (const float*)d_in[5];
    const float* be1s = (const float*)d_in[6];
    const float* W2s  = (const float*)d_in[7];
    const float* b2s  = (const float*)d_in[8];
    const float* bn_g = (const float*)d_in[9];
    const float* bn_b = (const float*)d_in[10];
    const float* fcW  = (const float*)d_in[11];
    const float* fcb  = (const float*)d_in[12];
    float* out = (float*)d_out;

    const int N = in_sizes[0] / 128;
    const int E = in_sizes[1] / 2;
    const int G = out_size / 64;
    const int L = in_sizes[3] / (128 * 128);
    const int* src = ei;
    const int* dst = ei + E;

    size_t off = 0;
    auto carve = [&](size_t bytes) -> void* {
        void* p = (char*)d_ws + off;
        off += (bytes + 255) & ~(size_t)255;
        return p;
    };
    int* deg    = (int*)carve((size_t)N * 4);
    int* cur    = (int*)carve((size_t)N * 4);
    int* ofs    = (int*)carve((size_t)(N + 1) * 4);
    int* bsum   = (int*)carve(4096 * 4);
    int* csr    = (int*)carve((size_t)E * 4);
    int* gstart = (int*)carve((size_t)(G + 1) * 4);
    unsigned short* hinH = (unsigned short*)carve((size_t)N * 128 * 2);
    unsigned short* hinL = (unsigned short*)carve((size_t)N * 128 * 2);
    unsigned short* h1H  = (unsigned short*)carve((size_t)N * 128 * 2);
    unsigned short* h1L  = (unsigned short*)carve((size_t)N * 128 * 2);
    float* hbuf  = (float*)carve((size_t)N * 128 * 4);
    unsigned short* wt1H = (unsigned short*)carve((size_t)L * 16384 * 2);
    unsigned short* wt1L = (unsigned short*)carve((size_t)L * 16384 * 2);
    unsigned short* wt2H = (unsigned short*)carve(16384 * 2);
    unsigned short* wt2L = (unsigned short*)carve(16384 * 2);
    float* b2p    = (float*)carve(128 * 4);
    float* colsum = (float*)carve(128 * 4);
    float* colsq  = (float*)carve(128 * 4);
    float* pooled = (float*)carve((size_t)G * 128 * 4);
    float* pscale = (float*)carve(128 * 4);
    float* pshift = (float*)carve(128 * 4);
    (void)ws_size; (void)n_in;

    // ---- weight prep for all layers (data-independent) ----
    int wtot = L * 16384;
    prep_w1_all<<<(wtot + 255) / 256, 256, 0, stream>>>(W1s, wt1H, wt1L, wtot);

    // ---- CSR build (once per call) ----
    zero2_kernel<<<(N + 255) / 256, 256, 0, stream>>>(deg, cur, N);
    hist_kernel<<<(E + 255) / 256, 256, 0, stream>>>(dst, deg, E);
    int nb1 = (N + 255) / 256;
    scan1_kernel<<<nb1, 256, 0, stream>>>(deg, ofs, bsum, N);
    scan2_kernel<<<1, 1024, 0, stream>>>(bsum, nb1);
    scan3_kernel<<<nb1, 256, 0, stream>>>(ofs, bsum, N, E);
    fill_kernel<<<(E + 255) / 256, 256, 0, stream>>>(src, dst, ofs, cur, csr, E);

    // ---- layers ----
    const float* hprev = x;
    int gemmBlocks = (N + 127) / 128;
    for (int l = 0; l < L; ++l) {
        agg_split<<<(N + 7) / 8, 256, 0, stream>>>(hprev, ofs, csr, hinH, hinL,
                                                   colsum, colsq, N);
        gemm_split<1><<<gemmBlocks, 256, 0, stream>>>(hinH, hinL,
                                                      wt1H + l * 16384, wt1L + l * 16384,
                                                      b1s + l * 128,
                                                      h1H, h1L, nullptr, colsum, colsq, N);
        w2t_fold<<<64, 256, 0, stream>>>(W2s + (size_t)l * 16384, b2s + l * 128,
                                         g1s + l * 128, be1s + l * 128,
                                         colsum, colsq, wt2H, wt2L, b2p, N);
        gemm_split<2><<<gemmBlocks, 256, 0, stream>>>(h1H, h1L, wt2H, wt2L, b2p,
                                                      nullptr, nullptr, hbuf, nullptr, nullptr, N);
        hprev = hbuf;
    }

    // ---- readout ----
    graph_bounds<<<(N + 255) / 256, 256, 0, stream>>>(batch, gstart, N, G);
    pool_kernel<<<(G + 7) / 8, 256, 0, stream>>>(hbuf, gstart, pooled, G);
    pool_stats<<<1, 1024, 0, stream>>>(pooled, bn_g, bn_b, pscale, pshift, G);
    final_fc<<<(G * 64 + 255) / 256, 256, 0, stream>>>(pooled, pscale, pshift, fcW, fcb,
                                                       out, G * 64);
}